// Round 1
// baseline (1375.959 us; speedup 1.0000x reference)
//
#include <hip/hip_runtime.h>
#include <hip/hip_bf16.h>

typedef short bf16x8 __attribute__((ext_vector_type(8)));
typedef float f32x4  __attribute__((ext_vector_type(4)));

#define MFMA_16x16x32_BF16 __builtin_amdgcn_mfma_f32_16x16x32_bf16

__device__ __forceinline__ unsigned short f2bf(float x) {
    unsigned int u = __builtin_bit_cast(unsigned int, x);
    u += 0x7FFFu + ((u >> 16) & 1u);   // round-to-nearest-even
    return (unsigned short)(u >> 16);
}

// ---------------------------------------------------------------------------
// Generic O[m,n] = sum_k X[m,k]*W[n,k] + bias[n]   (M=4096, N=1024, K=1024)
// mode 0: out bf16, layout [B=2][H=16][T=2048][D=64]  (q, k)
// mode 1: out bf16, layout [B=2][H=16][D=64][S=2048]  (v transposed)
// mode 2: out fp32, layout [M][N]                      (final projection)
// ---------------------------------------------------------------------------
__device__ __forceinline__ void gemm_core(const float* __restrict__ X,
                                          const float* __restrict__ W,
                                          const float* __restrict__ bias,
                                          void* __restrict__ outp, int mode,
                                          short* As, short* Bs) {
    const int tid  = threadIdx.x;
    const int m0   = blockIdx.y * 128;
    const int n0   = blockIdx.x * 128;
    const int w    = tid >> 6, lane = tid & 63;
    const int wm   = (w >> 1) * 64, wn = (w & 1) * 64;
    const int quad = lane >> 4, l16 = lane & 15;

    f32x4 acc[4][4];
#pragma unroll
    for (int i = 0; i < 4; ++i)
#pragma unroll
        for (int j = 0; j < 4; ++j) acc[i][j] = (f32x4){0.f, 0.f, 0.f, 0.f};

    for (int k0 = 0; k0 < 1024; k0 += 32) {
        __syncthreads();
#pragma unroll
        for (int c = 0; c < 4; ++c) {
            int idx = tid + 256 * c;          // 0..1023
            int row = idx >> 3;               // 0..127
            int kc  = (idx & 7) << 2;         // 0,4,...,28
            const float4 a  = *(const float4*)(X + (size_t)(m0 + row) * 1024 + k0 + kc);
            const float4 bv = *(const float4*)(W + (size_t)(n0 + row) * 1024 + k0 + kc);
            ushort4 ap = make_ushort4(f2bf(a.x),  f2bf(a.y),  f2bf(a.z),  f2bf(a.w));
            ushort4 bp = make_ushort4(f2bf(bv.x), f2bf(bv.y), f2bf(bv.z), f2bf(bv.w));
            *(ushort4*)(As + row * 40 + kc) = ap;   // 40-short pitch: 80B rows (16B-aligned, 2-way banks)
            *(ushort4*)(Bs + row * 40 + kc) = bp;
        }
        __syncthreads();
        bf16x8 af[4], bfr[4];
#pragma unroll
        for (int mi = 0; mi < 4; ++mi)
            af[mi] = *(const bf16x8*)(As + (wm + mi * 16 + l16) * 40 + quad * 8);
#pragma unroll
        for (int ni = 0; ni < 4; ++ni)
            bfr[ni] = *(const bf16x8*)(Bs + (wn + ni * 16 + l16) * 40 + quad * 8);
#pragma unroll
        for (int mi = 0; mi < 4; ++mi)
#pragma unroll
            for (int ni = 0; ni < 4; ++ni)
                acc[mi][ni] = MFMA_16x16x32_BF16(af[mi], bfr[ni], acc[mi][ni], 0, 0, 0);
    }

    // epilogue: D[row=m]=(quad*4+reg), D[col=n]=l16   (m89-verified)
    if (mode == 2) {
        float* Out = (float*)outp;
#pragma unroll
        for (int mi = 0; mi < 4; ++mi)
#pragma unroll
            for (int ni = 0; ni < 4; ++ni) {
                int n = n0 + wn + ni * 16 + l16;
                float bn = bias[n];
                int mbase = m0 + wm + mi * 16 + quad * 4;
#pragma unroll
                for (int r = 0; r < 4; ++r)
                    Out[(size_t)(mbase + r) * 1024 + n] = acc[mi][ni][r] + bn;
            }
    } else if (mode == 0) {
        unsigned short* Out = (unsigned short*)outp;
#pragma unroll
        for (int mi = 0; mi < 4; ++mi)
#pragma unroll
            for (int ni = 0; ni < 4; ++ni) {
                int n = n0 + wn + ni * 16 + l16;
                float bn = bias[n];
                int h = n >> 6, d = n & 63;
                int mbase = m0 + wm + mi * 16 + quad * 4;
#pragma unroll
                for (int r = 0; r < 4; ++r) {
                    int mm = mbase + r;
                    int bb = mm >> 11, t = mm & 2047;
                    Out[(((size_t)(bb * 16 + h)) * 2048 + t) * 64 + d] =
                        f2bf(acc[mi][ni][r] + bn);
                }
            }
    } else {  // mode 1: v transposed, pack 4 consecutive s per lane
        unsigned short* Out = (unsigned short*)outp;
#pragma unroll
        for (int mi = 0; mi < 4; ++mi)
#pragma unroll
            for (int ni = 0; ni < 4; ++ni) {
                int n = n0 + wn + ni * 16 + l16;
                float bn = bias[n];
                int h = n >> 6, d = n & 63;
                int mbase = m0 + wm + mi * 16 + quad * 4;  // s base (mult of 4)
                int bb = mbase >> 11, s = mbase & 2047;
                ushort4 pk = make_ushort4(f2bf(acc[mi][ni][0] + bn), f2bf(acc[mi][ni][1] + bn),
                                          f2bf(acc[mi][ni][2] + bn), f2bf(acc[mi][ni][3] + bn));
                *(ushort4*)(Out + (((size_t)(bb * 16 + h)) * 64 + d) * 2048 + s) = pk;
            }
    }
}

__global__ __launch_bounds__(256) void proj_qkv_kernel(
    const float* __restrict__ q_in, const float* __restrict__ k_in, const float* __restrict__ v_in,
    const float* __restrict__ Wq, const float* __restrict__ Wk, const float* __restrict__ Wv,
    const float* __restrict__ bq, const float* __restrict__ bk, const float* __restrict__ bv,
    unsigned short* __restrict__ q_bf, unsigned short* __restrict__ k_bf,
    unsigned short* __restrict__ vT) {
    __shared__ short lds[2 * 128 * 40];
    const int z = blockIdx.z;
    const float* X = (z == 0) ? q_in : (z == 1) ? k_in : v_in;
    const float* W = (z == 0) ? Wq : (z == 1) ? Wk : Wv;
    const float* B = (z == 0) ? bq : (z == 1) ? bk : bv;
    void* O = (z == 0) ? (void*)q_bf : (z == 1) ? (void*)k_bf : (void*)vT;
    gemm_core(X, W, B, O, (z == 2) ? 1 : 0, lds, lds + 128 * 40);
}

__global__ __launch_bounds__(256) void proj_o_kernel(const float* __restrict__ X,
                                                     const float* __restrict__ Wo,
                                                     const float* __restrict__ bo,
                                                     float* __restrict__ Out) {
    __shared__ short lds[2 * 128 * 40];
    gemm_core(X, Wo, bo, (void*)Out, 2, lds, lds + 128 * 40);
}

// ---------------------------------------------------------------------------
// Flash attention with additive biases. 1 wave owns 16 query rows; 4 lockstep
// waves per block (same bh -> shared L2/L1 lines for k/v fragments).
// ---------------------------------------------------------------------------
__global__ __launch_bounds__(256) void attn_kernel(
    const unsigned short* __restrict__ q_bf, const unsigned short* __restrict__ k_bf,
    const unsigned short* __restrict__ vT,
    const float* __restrict__ spatial, const float* __restrict__ dirb,
    const float* __restrict__ attn_mask, const unsigned char* __restrict__ padm,
    float* __restrict__ attn_out) {
    __shared__ float          sc_all[4][16][68];
    __shared__ unsigned short P_all[4][16][72];
    __shared__ float          alpha_all[4][16];
    __shared__ float          lsum_all[4][16];

    const int w = threadIdx.x >> 6, lane = threadIdx.x & 63;
    const int gw = blockIdx.x * 4 + w;          // 0..4095
    const int bh = gw >> 7;                     // b*16+h, 0..31
    const int t0 = (gw & 127) << 4;
    const int b  = bh >> 4, h = bh & 15;
    const int quad = lane >> 4, l16 = lane & 15;
    float (*sc)[68]          = sc_all[w];
    unsigned short (*Pl)[72] = P_all[w];

    // q A-fragments, held for the whole block: A[m=l16][k=quad*8+j]
    const unsigned short* qbase = q_bf + ((size_t)bh * 2048 + t0) * 64;
    bf16x8 qf[2];
    qf[0] = *(const bf16x8*)(qbase + l16 * 64 + quad * 8);
    qf[1] = *(const bf16x8*)(qbase + l16 * 64 + 32 + quad * 8);

    const unsigned short* kbase = k_bf + (size_t)bh * 2048 * 64;
    const unsigned short* vbase = vT + (size_t)bh * 64 * 2048;
    const float* sb_row = spatial  + ((size_t)bh * 2048 + t0) * 2048;
    const float* db_row = dirb     + ((size_t)bh * 2048 + t0) * 2048;
    const float* am_row = attn_mask + (size_t)t0 * 2048;
    const unsigned char* pm = padm + (size_t)b * 2048;

    const int srow = lane >> 2, scol0 = (lane & 3) << 4;

    f32x4 oacc[4];
#pragma unroll
    for (int ni = 0; ni < 4; ++ni) oacc[ni] = (f32x4){0.f, 0.f, 0.f, 0.f};
    float m_run = -3.0e38f, l_run = 0.f;
    const float NEG = -3.0e38f;

    for (int st = 0; st < 32; ++st) {
        const int s0 = st << 6;
        // ---- QK^T for 16t x 64s tile ----
        f32x4 sacc[4];
#pragma unroll
        for (int ni = 0; ni < 4; ++ni) sacc[ni] = (f32x4){0.f, 0.f, 0.f, 0.f};
#pragma unroll
        for (int ki = 0; ki < 2; ++ki)
#pragma unroll
            for (int ni = 0; ni < 4; ++ni) {
                bf16x8 kf = *(const bf16x8*)(kbase + (size_t)(s0 + ni * 16 + l16) * 64 +
                                             ki * 32 + quad * 8);
                sacc[ni] = MFMA_16x16x32_BF16(qf[ki], kf, sacc[ni], 0, 0, 0);
            }
#pragma unroll
        for (int ni = 0; ni < 4; ++ni)
#pragma unroll
            for (int r = 0; r < 4; ++r)
                sc[quad * 4 + r][ni * 16 + l16] = sacc[ni][r] * 0.125f;
        __syncthreads();

        // ---- biases + online softmax (lane owns row srow, cols scol0..+15) ----
        const float* sbp = sb_row + (size_t)srow * 2048 + s0 + scol0;
        const float* dbp = db_row + (size_t)srow * 2048 + s0 + scol0;
        const float* amp = am_row + (size_t)srow * 2048 + s0 + scol0;
        uint4 pv4 = *(const uint4*)(pm + s0 + scol0);
        unsigned int pw[4] = {pv4.x, pv4.y, pv4.z, pv4.w};
        float vals[16];
#pragma unroll
        for (int c = 0; c < 4; ++c) {
            float4 s4  = *(const float4*)&sc[srow][scol0 + 4 * c];
            float4 a4  = *(const float4*)(amp + 4 * c);
            float4 b4  = *(const float4*)(sbp + 4 * c);
            float4 d4  = *(const float4*)(dbp + 4 * c);
            float v0 = s4.x + a4.x + b4.x + d4.x;
            float v1 = s4.y + a4.y + b4.y + d4.y;
            float v2 = s4.z + a4.z + b4.z + d4.z;
            float v3 = s4.w + a4.w + b4.w + d4.w;
            unsigned int pb = pw[c];
            if (pb & 0x000000FFu) v0 = NEG;
            if (pb & 0x0000FF00u) v1 = NEG;
            if (pb & 0x00FF0000u) v2 = NEG;
            if (pb & 0xFF000000u) v3 = NEG;
            vals[4 * c + 0] = v0; vals[4 * c + 1] = v1;
            vals[4 * c + 2] = v2; vals[4 * c + 3] = v3;
        }
        float rmax = vals[0];
#pragma unroll
        for (int i = 1; i < 16; ++i) rmax = fmaxf(rmax, vals[i]);
        rmax = fmaxf(rmax, __shfl_xor(rmax, 1));
        rmax = fmaxf(rmax, __shfl_xor(rmax, 2));
        const float mnew  = fmaxf(m_run, rmax);
        const float alpha = __expf(m_run - mnew);
        float ssum = 0.f;
#pragma unroll
        for (int c = 0; c < 4; ++c) {
            float p0 = __expf(vals[4 * c + 0] - mnew);
            float p1 = __expf(vals[4 * c + 1] - mnew);
            float p2 = __expf(vals[4 * c + 2] - mnew);
            float p3 = __expf(vals[4 * c + 3] - mnew);
            ssum += p0 + p1 + p2 + p3;
            *(ushort4*)&Pl[srow][scol0 + 4 * c] =
                make_ushort4(f2bf(p0), f2bf(p1), f2bf(p2), f2bf(p3));
        }
        ssum += __shfl_xor(ssum, 1);
        ssum += __shfl_xor(ssum, 2);
        l_run = l_run * alpha + ssum;
        m_run = mnew;
        if ((lane & 3) == 0) alpha_all[w][srow] = alpha;
        __syncthreads();

        // ---- rescale O accumulator, then PV ----
        float al4[4];
#pragma unroll
        for (int r = 0; r < 4; ++r) al4[r] = alpha_all[w][quad * 4 + r];
#pragma unroll
        for (int ni = 0; ni < 4; ++ni)
#pragma unroll
            for (int r = 0; r < 4; ++r) oacc[ni][r] *= al4[r];
#pragma unroll
        for (int ki = 0; ki < 2; ++ki) {
            bf16x8 pf = *(const bf16x8*)&Pl[l16][ki * 32 + quad * 8];
#pragma unroll
            for (int ni = 0; ni < 4; ++ni) {
                bf16x8 vf = *(const bf16x8*)(vbase + (size_t)(ni * 16 + l16) * 2048 +
                                             s0 + ki * 32 + quad * 8);
                oacc[ni] = MFMA_16x16x32_BF16(pf, vf, oacc[ni], 0, 0, 0);
            }
        }
        __syncthreads();
    }

    if ((lane & 3) == 0) lsum_all[w][srow] = l_run;
    __syncthreads();
    float inv[4];
#pragma unroll
    for (int r = 0; r < 4; ++r) inv[r] = 1.0f / lsum_all[w][quad * 4 + r];
    float* ob = attn_out + ((size_t)b * 2048 + t0) * 1024 + h * 64;
#pragma unroll
    for (int ni = 0; ni < 4; ++ni)
#pragma unroll
        for (int r = 0; r < 4; ++r)
            ob[(size_t)(quad * 4 + r) * 1024 + ni * 16 + l16] = oacc[ni][r] * inv[r];
}

// ---------------------------------------------------------------------------
extern "C" void kernel_launch(void* const* d_in, const int* in_sizes, int n_in,
                              void* d_out, int out_size, void* d_ws, size_t ws_size,
                              hipStream_t stream) {
    const float* query   = (const float*)d_in[0];
    const float* key     = (const float*)d_in[1];
    const float* value   = (const float*)d_in[2];
    const float* spatial = (const float*)d_in[3];
    const float* dirb    = (const float*)d_in[4];
    const unsigned char* padm = (const unsigned char*)d_in[5];
    const float* amask   = (const float*)d_in[6];
    const float* Wq = (const float*)d_in[7];
    const float* bq = (const float*)d_in[8];
    const float* Wk = (const float*)d_in[9];
    const float* bk = (const float*)d_in[10];
    const float* Wv = (const float*)d_in[11];
    const float* bv = (const float*)d_in[12];
    const float* Wo = (const float*)d_in[13];
    const float* bo = (const float*)d_in[14];

    const size_t NE = (size_t)2 * 16 * 2048 * 64;  // 4,194,304 elems per tensor
    unsigned short* q_bf = (unsigned short*)d_ws;
    unsigned short* k_bf = q_bf + NE;
    unsigned short* vT   = k_bf + NE;
    float* attn_o        = (float*)(vT + NE);      // 16 MB fp32

    proj_qkv_kernel<<<dim3(8, 32, 3), 256, 0, stream>>>(
        query, key, value, Wq, Wk, Wv, bq, bk, bv, q_bf, k_bf, vT);
    attn_kernel<<<dim3(1024), 256, 0, stream>>>(
        q_bf, k_bf, vT, spatial, dirb, amask, padm, attn_o);
    proj_o_kernel<<<dim3(8, 32, 1), 256, 0, stream>>>(attn_o, Wo, bo, (float*)d_out);
}